// Round 4
// baseline (472.492 us; speedup 1.0000x reference)
//
#include <hip/hip_runtime.h>

#define LN_EPS 1e-5f

typedef __attribute__((ext_vector_type(8))) short bf16x8;
typedef __attribute__((ext_vector_type(4))) float f32x4;

__device__ __forceinline__ unsigned short f2bf(float f) {
    union { float f; unsigned u; } x; x.f = f;
    unsigned r = (x.u + 0x7FFFu + ((x.u >> 16) & 1u)) >> 16;
    return (unsigned short)r;
}
__device__ __forceinline__ float bfbits2f(unsigned hi) {  // hi = bf16 bits already in [31:16]
    union { unsigned u; float f; } x; x.u = hi; return x.f;
}

// ---------- degree / CSR build ----------
__global__ void zero_counts_k(int* counts, int n) {
    int i = blockIdx.x * blockDim.x + threadIdx.x;
    if (i < n) counts[i] = 0;
}

__global__ void count_k(const int* __restrict__ dst, int* counts, int nE) {
    int e = blockIdx.x * blockDim.x + threadIdx.x;
    if (e < nE) atomicAdd(&counts[dst[e]], 1);
}

__global__ __launch_bounds__(256) void scan1_k(const int* __restrict__ counts,
                                               int* __restrict__ incl,
                                               int* __restrict__ bsums, int n) {
    __shared__ int s[256];
    int i = blockIdx.x * 256 + threadIdx.x;
    int v = (i < n) ? counts[i] : 0;
    s[threadIdx.x] = v;
    __syncthreads();
    for (int off = 1; off < 256; off <<= 1) {
        int t = (threadIdx.x >= off) ? s[threadIdx.x - off] : 0;
        __syncthreads();
        s[threadIdx.x] += t;
        __syncthreads();
    }
    if (i < n) incl[i] = s[threadIdx.x];
    if (threadIdx.x == 255) bsums[blockIdx.x] = s[255];
}

__global__ __launch_bounds__(256) void scan2_k(int* bsums, int nb) {
    __shared__ int s[256];
    int v = (threadIdx.x < nb) ? bsums[threadIdx.x] : 0;
    s[threadIdx.x] = v;
    __syncthreads();
    for (int off = 1; off < 256; off <<= 1) {
        int t = (threadIdx.x >= off) ? s[threadIdx.x - off] : 0;
        __syncthreads();
        s[threadIdx.x] += t;
        __syncthreads();
    }
    if (threadIdx.x < nb) bsums[threadIdx.x] = s[threadIdx.x] - v;
}

__global__ __launch_bounds__(256) void scan3_k(const int* __restrict__ counts,
                                               const int* __restrict__ incl,
                                               const int* __restrict__ bsums,
                                               int* __restrict__ rowptr,
                                               int* __restrict__ cursor,
                                               float* __restrict__ dinv, int n, int nE) {
    int i = blockIdx.x * 256 + threadIdx.x;
    if (i < n) {
        int ex = incl[i] - counts[i] + bsums[blockIdx.x];
        rowptr[i] = ex;
        cursor[i] = ex;
        dinv[i] = rsqrtf((float)(counts[i] + 1));
    }
    if (i == n) rowptr[n] = nE;
}

// bucket cursors: bucket b covers dst nodes [b*64, (b+1)*64); base = rowptr[b*64]
__global__ void bcur_init_k(const int* __restrict__ rowptr, int* __restrict__ bcur, int nbkt) {
    int b = blockIdx.x * blockDim.x + threadIdx.x;
    if (b < nbkt) bcur[b] = rowptr[b * 64];
}

// pass 1: partition edges into dst-buckets; positions within a bucket are
// handed out sequentially -> dense line-filling writes to pairs[]
__global__ void scatter_pairs_k(const int* __restrict__ src, const int* __restrict__ dst,
                                int* bcur, int2* __restrict__ pairs, int nE) {
    int e = blockIdx.x * blockDim.x + threadIdx.x;
    if (e < nE) {
        int d = dst[e];
        int pos = atomicAdd(&bcur[d >> 6], 1);
        pairs[pos] = make_int2(src[e], d);
    }
}

// pass 2: pairs are bucket-contiguous, so final eidx writes land in a ~4KB
// dense region per bucket -> lines fill in L2 before write-back
__global__ void scatter_final_k(const int2* __restrict__ pairs, int* cursor,
                                int* __restrict__ eidx, int nE) {
    int e = blockIdx.x * blockDim.x + threadIdx.x;
    if (e < nE) {
        int2 p = pairs[e];
        int pos = atomicAdd(&cursor[p.y], 1);
        eidx[pos] = p.x;
    }
}

// ---------- conversions / packing ----------
__global__ void convx_k(const float* __restrict__ X, unsigned short* __restrict__ Xb,
                        int total, int total_pad) {
    int i = blockIdx.x * blockDim.x + threadIdx.x;
    if (i < total_pad) Xb[i] = (i < total) ? f2bf(X[i]) : (unsigned short)0;
}

// Pack both W1 and W2 into B-fragment-contiguous bf16 layout:
// Wp[(((kc*128 + col)*4 + kb)*8) + j] = W[(kc*32 + kb*8 + j)*128 + col]
__global__ void packw_k(const float* __restrict__ W1, const float* __restrict__ W2,
                        unsigned short* __restrict__ Wp1, unsigned short* __restrict__ Wp2) {
    int idx = blockIdx.x * blockDim.x + threadIdx.x;  // 0..32767
    const float* W = (idx < 16384) ? W1 : W2;
    unsigned short* Wp = (idx < 16384) ? Wp1 : Wp2;
    int t = idx & 16383;
    int k = t >> 7, col = t & 127;
    int kc = k >> 5, kr = k & 31, kb = kr >> 3, j = kr & 7;
    Wp[(((kc * 128 + col) * 4 + kb) * 8) + j] = f2bf(W[k * 128 + col]);
}

// ---------- MFMA GEMM: Y[r,:] = bf16( dinv[r] * (Xb[r,:] @ W) ) ----------
__global__ __launch_bounds__(256) void mfma_gemm_k(const unsigned short* __restrict__ Xb,
                                                   const unsigned short* __restrict__ Wp,
                                                   const float* __restrict__ dinv,
                                                   unsigned short* __restrict__ Y, int n) {
    int wid = threadIdx.x >> 6;
    int lane = threadIdx.x & 63;
    int rgrp = wid & 1;
    int cgrp = wid >> 1;
    int row0 = blockIdx.x * 64 + rgrp * 32;
    int m = lane & 15;
    int kb = lane >> 4;  // 0..3

    f32x4 acc[2][4] = {};
#pragma unroll
    for (int kc = 0; kc < 4; ++kc) {
        bf16x8 a[2], b[4];
#pragma unroll
        for (int rs = 0; rs < 2; ++rs) {
            int r = row0 + rs * 16 + m;
            a[rs] = *(const bf16x8*)(Xb + (size_t)r * 128 + kc * 32 + kb * 8);
        }
#pragma unroll
        for (int cf = 0; cf < 4; ++cf) {
            int col = cgrp * 64 + cf * 16 + m;
            b[cf] = *(const bf16x8*)(Wp + (((kc * 128 + col) * 4 + kb) * 8));
        }
#pragma unroll
        for (int rs = 0; rs < 2; ++rs)
#pragma unroll
            for (int cf = 0; cf < 4; ++cf)
                acc[rs][cf] = __builtin_amdgcn_mfma_f32_16x16x32_bf16(a[rs], b[cf], acc[rs][cf], 0, 0, 0);
    }
    // D layout: row = (lane>>4)*4 + reg, col = lane&15
#pragma unroll
    for (int rs = 0; rs < 2; ++rs) {
        int rbase = row0 + rs * 16 + kb * 4;
#pragma unroll
        for (int r = 0; r < 4; ++r) {
            int row = rbase + r;
            if (row >= n) continue;
            float dv = dinv[row];
#pragma unroll
            for (int cf = 0; cf < 4; ++cf) {
                int col = cgrp * 64 + cf * 16 + m;
                Y[(size_t)row * 128 + col] = f2bf(acc[rs][cf][r] * dv);
            }
        }
    }
}

// ---------- fused gather-aggregate + bias + LN + ReLU ----------
template <bool OUT_BF16>
__global__ __launch_bounds__(256) void agg_ln_k(const unsigned short* __restrict__ Hs,
                                                const float* __restrict__ dinv,
                                                const int* __restrict__ rowptr,
                                                const int* __restrict__ eidx,
                                                const float* __restrict__ bias,
                                                const float* __restrict__ g,
                                                const float* __restrict__ beta,
                                                void* __restrict__ out, int n) {
    int wave = (blockIdx.x * blockDim.x + threadIdx.x) >> 6;
    int lane = threadIdx.x & 63;
    if (wave >= n) return;
    const unsigned* H4 = (const unsigned*)Hs;  // one uint = 2 bf16
    unsigned v0 = H4[(size_t)wave * 64 + lane];
    float ax = bfbits2f(v0 << 16);
    float ay = bfbits2f(v0 & 0xFFFF0000u);
    int beg = rowptr[wave];
    int end = rowptr[wave + 1];
    int e = beg;
    for (; e + 3 < end; e += 4) {
        int s0 = eidx[e], s1 = eidx[e + 1], s2 = eidx[e + 2], s3 = eidx[e + 3];
        unsigned u0 = H4[(size_t)s0 * 64 + lane];
        unsigned u1 = H4[(size_t)s1 * 64 + lane];
        unsigned u2 = H4[(size_t)s2 * 64 + lane];
        unsigned u3 = H4[(size_t)s3 * 64 + lane];
        ax += bfbits2f(u0 << 16) + bfbits2f(u1 << 16) + bfbits2f(u2 << 16) + bfbits2f(u3 << 16);
        ay += bfbits2f(u0 & 0xFFFF0000u) + bfbits2f(u1 & 0xFFFF0000u) +
              bfbits2f(u2 & 0xFFFF0000u) + bfbits2f(u3 & 0xFFFF0000u);
    }
    for (; e < end; ++e) {
        unsigned u0 = H4[(size_t)eidx[e] * 64 + lane];
        ax += bfbits2f(u0 << 16);
        ay += bfbits2f(u0 & 0xFFFF0000u);
    }
    float dt = dinv[wave];
    float vx = ax * dt + bias[2 * lane];
    float vy = ay * dt + bias[2 * lane + 1];
    float sum = vx + vy;
#pragma unroll
    for (int off = 32; off > 0; off >>= 1) sum += __shfl_down(sum, off);
    sum = __shfl(sum, 0);
    float mu = sum * (1.0f / 128.0f);
    float dx = vx - mu, dy = vy - mu;
    float vs = dx * dx + dy * dy;
#pragma unroll
    for (int off = 32; off > 0; off >>= 1) vs += __shfl_down(vs, off);
    vs = __shfl(vs, 0);
    float rstd = rsqrtf(vs * (1.0f / 128.0f) + LN_EPS);
    float o0 = fmaxf(dx * rstd * g[2 * lane] + beta[2 * lane], 0.0f);
    float o1 = fmaxf(dy * rstd * g[2 * lane + 1] + beta[2 * lane + 1], 0.0f);
    if (OUT_BF16) {
        unsigned pack = (unsigned)f2bf(o0) | ((unsigned)f2bf(o1) << 16);
        ((unsigned*)out)[(size_t)wave * 64 + lane] = pack;
    } else {
        ((float2*)out)[(size_t)wave * 64 + lane] = make_float2(o0, o1);
    }
}

extern "C" void kernel_launch(void* const* d_in, const int* in_sizes, int n_in,
                              void* d_out, int out_size, void* d_ws, size_t ws_size,
                              hipStream_t stream) {
    const float* x   = (const float*)d_in[0];
    const int*   ei  = (const int*)d_in[1];
    const float* W1  = (const float*)d_in[2];
    const float* b1  = (const float*)d_in[3];
    const float* g1  = (const float*)d_in[4];
    const float* be1 = (const float*)d_in[5];
    const float* W2  = (const float*)d_in[6];
    const float* b2  = (const float*)d_in[7];
    const float* g2  = (const float*)d_in[8];
    const float* be2 = (const float*)d_in[9];
    float* out = (float*)d_out;

    int n  = in_sizes[0] / 128;   // 50000
    int nE = in_sizes[1] / 2;     // 800000
    const int* src = ei;
    const int* dst = ei + nE;

    int nblk64 = (n + 63) / 64;       // GEMM blocks
    int npad   = nblk64 * 64;         // padded rows for OOB-safe frag loads
    int nbkt   = (n + 63) / 64;       // scatter buckets (64 dst-nodes each)

    char* p = (char*)d_ws;
    auto carve = [&](size_t bytes) {
        char* r = p;
        p += (bytes + 255) & ~(size_t)255;
        return r;
    };
    float* dinv   = (float*)carve((size_t)n * 4);
    int*   counts = (int*)carve((size_t)n * 4);
    int*   incl   = (int*)carve((size_t)n * 4);
    int*   bsums  = (int*)carve(256 * 4);
    int*   rowptr = (int*)carve((size_t)(n + 1) * 4);
    int*   cursor = (int*)carve((size_t)n * 4);
    int*   bcur   = (int*)carve((size_t)nbkt * 4);
    int*   eidx   = (int*)carve((size_t)nE * 4);
    int2*  pairs  = (int2*)carve((size_t)nE * 8);
    unsigned short* Wp1 = (unsigned short*)carve(16384 * 2);
    unsigned short* Wp2 = (unsigned short*)carve(16384 * 2);
    unsigned short* Xb  = (unsigned short*)carve((size_t)npad * 128 * 2);
    unsigned short* Hs  = (unsigned short*)carve((size_t)npad * 128 * 2);
    unsigned short* Hb  = (unsigned short*)carve((size_t)npad * 128 * 2);

    dim3 blk(256);
    int nb_n = (n + 255) / 256;
    int nb_e = (nE + 255) / 256;
    int total = n * 128, total_pad = npad * 128;

    // CSR build + dinv
    zero_counts_k<<<nb_n, blk, 0, stream>>>(counts, n);
    count_k<<<nb_e, blk, 0, stream>>>(dst, counts, nE);
    scan1_k<<<nb_n, blk, 0, stream>>>(counts, incl, bsums, n);
    scan2_k<<<1, blk, 0, stream>>>(bsums, nb_n);
    scan3_k<<<(n + 256) / 256, blk, 0, stream>>>(counts, incl, bsums, rowptr, cursor, dinv, n, nE);
    bcur_init_k<<<(nbkt + 255) / 256, blk, 0, stream>>>(rowptr, bcur, nbkt);
    scatter_pairs_k<<<nb_e, blk, 0, stream>>>(src, dst, bcur, pairs, nE);
    scatter_final_k<<<nb_e, blk, 0, stream>>>(pairs, cursor, eidx, nE);

    // conversions
    convx_k<<<(total_pad + 255) / 256, blk, 0, stream>>>(x, Xb, total, total_pad);
    packw_k<<<32768 / 256, blk, 0, stream>>>(W1, W2, Wp1, Wp2);

    int nwave_blocks = (n + 3) / 4;

    // layer 1
    mfma_gemm_k<<<nblk64, blk, 0, stream>>>(Xb, Wp1, dinv, Hs, n);
    agg_ln_k<true><<<nwave_blocks, blk, 0, stream>>>(Hs, dinv, rowptr, eidx, b1, g1, be1, Hb, n);

    // layer 2
    mfma_gemm_k<<<nblk64, blk, 0, stream>>>(Hb, Wp2, dinv, Hs, n);
    agg_ln_k<false><<<nwave_blocks, blk, 0, stream>>>(Hs, dinv, rowptr, eidx, b2, g2, be2, out, n);
}

// Round 5
// 386.073 us; speedup vs baseline: 1.2238x; 1.2238x over previous
//
#include <hip/hip_runtime.h>

#define LN_EPS 1e-5f

typedef __attribute__((ext_vector_type(8))) short bf16x8;
typedef __attribute__((ext_vector_type(4))) float f32x4;

__device__ __forceinline__ unsigned short f2bf(float f) {
    union { float f; unsigned u; } x; x.f = f;
    unsigned r = (x.u + 0x7FFFu + ((x.u >> 16) & 1u)) >> 16;
    return (unsigned short)r;
}
__device__ __forceinline__ float bfbits2f(unsigned hi) {  // hi = bf16 bits already in [31:16]
    union { unsigned u; float f; } x; x.u = hi; return x.f;
}

// ---------- linked-list build (no CSR, no positional scatter) ----------
__global__ void init_k(int* head, int* counts, int n) {
    int i = blockIdx.x * blockDim.x + threadIdx.x;
    if (i < n) { head[i] = -1; counts[i] = 0; }
}

// next[e] written at index e (coalesced, dense). head/counts are 200KB,
// L2-resident, fan-in ~deg(16) per address -> low contention.
__global__ void build_k(const int* __restrict__ src, const int* __restrict__ dst,
                        int* head, int* __restrict__ nxt, int* counts, int nE) {
    int e = blockIdx.x * blockDim.x + threadIdx.x;
    if (e < nE) {
        int d = dst[e];
        nxt[e] = atomicExch(&head[d], e);
        atomicAdd(&counts[d], 1);
    }
}

__global__ void dinv_k(const int* __restrict__ counts, float* __restrict__ dinv, int n) {
    int i = blockIdx.x * blockDim.x + threadIdx.x;
    if (i < n) dinv[i] = rsqrtf((float)(counts[i] + 1));  // +1 self-loop
}

// ---------- conversions / packing ----------
__global__ void convx_k(const float* __restrict__ X, unsigned short* __restrict__ Xb,
                        int total, int total_pad) {
    int i = blockIdx.x * blockDim.x + threadIdx.x;
    if (i < total_pad) Xb[i] = (i < total) ? f2bf(X[i]) : (unsigned short)0;
}

// Pack both W1 and W2 into B-fragment-contiguous bf16 layout:
// Wp[(((kc*128 + col)*4 + kb)*8) + j] = W[(kc*32 + kb*8 + j)*128 + col]
__global__ void packw_k(const float* __restrict__ W1, const float* __restrict__ W2,
                        unsigned short* __restrict__ Wp1, unsigned short* __restrict__ Wp2) {
    int idx = blockIdx.x * blockDim.x + threadIdx.x;  // 0..32767
    const float* W = (idx < 16384) ? W1 : W2;
    unsigned short* Wp = (idx < 16384) ? Wp1 : Wp2;
    int t = idx & 16383;
    int k = t >> 7, col = t & 127;
    int kc = k >> 5, kr = k & 31, kb = kr >> 3, j = kr & 7;
    Wp[(((kc * 128 + col) * 4 + kb) * 8) + j] = f2bf(W[k * 128 + col]);
}

// ---------- MFMA GEMM: Y[r,:] = bf16( dinv[r] * (Xb[r,:] @ W) ) ----------
__global__ __launch_bounds__(256) void mfma_gemm_k(const unsigned short* __restrict__ Xb,
                                                   const unsigned short* __restrict__ Wp,
                                                   const float* __restrict__ dinv,
                                                   unsigned short* __restrict__ Y, int n) {
    int wid = threadIdx.x >> 6;
    int lane = threadIdx.x & 63;
    int rgrp = wid & 1;
    int cgrp = wid >> 1;
    int row0 = blockIdx.x * 64 + rgrp * 32;
    int m = lane & 15;
    int kb = lane >> 4;  // 0..3

    f32x4 acc[2][4] = {};
#pragma unroll
    for (int kc = 0; kc < 4; ++kc) {
        bf16x8 a[2], b[4];
#pragma unroll
        for (int rs = 0; rs < 2; ++rs) {
            int r = row0 + rs * 16 + m;
            a[rs] = *(const bf16x8*)(Xb + (size_t)r * 128 + kc * 32 + kb * 8);
        }
#pragma unroll
        for (int cf = 0; cf < 4; ++cf) {
            int col = cgrp * 64 + cf * 16 + m;
            b[cf] = *(const bf16x8*)(Wp + (((kc * 128 + col) * 4 + kb) * 8));
        }
#pragma unroll
        for (int rs = 0; rs < 2; ++rs)
#pragma unroll
            for (int cf = 0; cf < 4; ++cf)
                acc[rs][cf] = __builtin_amdgcn_mfma_f32_16x16x32_bf16(a[rs], b[cf], acc[rs][cf], 0, 0, 0);
    }
    // D layout: row = (lane>>4)*4 + reg, col = lane&15
#pragma unroll
    for (int rs = 0; rs < 2; ++rs) {
        int rbase = row0 + rs * 16 + kb * 4;
#pragma unroll
        for (int r = 0; r < 4; ++r) {
            int row = rbase + r;
            if (row >= n) continue;
            float dv = dinv[row];
#pragma unroll
            for (int cf = 0; cf < 4; ++cf) {
                int col = cgrp * 64 + cf * 16 + m;
                Y[(size_t)row * 128 + col] = f2bf(acc[rs][cf][r] * dv);
            }
        }
    }
}

// ---------- fused list-walk aggregate + bias + LN + ReLU ----------
// One wave per node; walks the dst's in-edge linked list. Hs is bf16 with
// dinv[src] folded in. Lane holds dims {2*lane, 2*lane+1}.
template <bool OUT_BF16>
__global__ __launch_bounds__(256) void agg_ln_k(const unsigned short* __restrict__ Hs,
                                                const float* __restrict__ dinv,
                                                const int* __restrict__ head,
                                                const int* __restrict__ nxt,
                                                const int* __restrict__ srcArr,
                                                const float* __restrict__ bias,
                                                const float* __restrict__ g,
                                                const float* __restrict__ beta,
                                                void* __restrict__ out, int n) {
    int wave = (blockIdx.x * blockDim.x + threadIdx.x) >> 6;
    int lane = threadIdx.x & 63;
    if (wave >= n) return;
    const unsigned* H4 = (const unsigned*)Hs;  // one uint = 2 bf16
    unsigned v0 = H4[(size_t)wave * 64 + lane];
    float ax = bfbits2f(v0 << 16);
    float ay = bfbits2f(v0 & 0xFFFF0000u);
    int e = head[wave];
    while (e >= 0) {
        int s = srcArr[e];     // uniform across wave (broadcast)
        int en = nxt[e];       // next hop issued before the row gather lands
        unsigned u = H4[(size_t)s * 64 + lane];
        ax += bfbits2f(u << 16);
        ay += bfbits2f(u & 0xFFFF0000u);
        e = en;
    }
    float dt = dinv[wave];
    float vx = ax * dt + bias[2 * lane];
    float vy = ay * dt + bias[2 * lane + 1];
    float sum = vx + vy;
#pragma unroll
    for (int off = 32; off > 0; off >>= 1) sum += __shfl_down(sum, off);
    sum = __shfl(sum, 0);
    float mu = sum * (1.0f / 128.0f);
    float dx = vx - mu, dy = vy - mu;
    float vs = dx * dx + dy * dy;
#pragma unroll
    for (int off = 32; off > 0; off >>= 1) vs += __shfl_down(vs, off);
    vs = __shfl(vs, 0);
    float rstd = rsqrtf(vs * (1.0f / 128.0f) + LN_EPS);
    float o0 = fmaxf(dx * rstd * g[2 * lane] + beta[2 * lane], 0.0f);
    float o1 = fmaxf(dy * rstd * g[2 * lane + 1] + beta[2 * lane + 1], 0.0f);
    if (OUT_BF16) {
        unsigned pack = (unsigned)f2bf(o0) | ((unsigned)f2bf(o1) << 16);
        ((unsigned*)out)[(size_t)wave * 64 + lane] = pack;
    } else {
        ((float2*)out)[(size_t)wave * 64 + lane] = make_float2(o0, o1);
    }
}

extern "C" void kernel_launch(void* const* d_in, const int* in_sizes, int n_in,
                              void* d_out, int out_size, void* d_ws, size_t ws_size,
                              hipStream_t stream) {
    const float* x   = (const float*)d_in[0];
    const int*   ei  = (const int*)d_in[1];
    const float* W1  = (const float*)d_in[2];
    const float* b1  = (const float*)d_in[3];
    const float* g1  = (const float*)d_in[4];
    const float* be1 = (const float*)d_in[5];
    const float* W2  = (const float*)d_in[6];
    const float* b2  = (const float*)d_in[7];
    const float* g2  = (const float*)d_in[8];
    const float* be2 = (const float*)d_in[9];
    float* out = (float*)d_out;

    int n  = in_sizes[0] / 128;   // 50000
    int nE = in_sizes[1] / 2;     // 800000
    const int* src = ei;
    const int* dst = ei + nE;

    int nblk64 = (n + 63) / 64;   // GEMM blocks
    int npad   = nblk64 * 64;     // padded rows for OOB-safe frag loads

    char* p = (char*)d_ws;
    auto carve = [&](size_t bytes) {
        char* r = p;
        p += (bytes + 255) & ~(size_t)255;
        return r;
    };
    float* dinv   = (float*)carve((size_t)n * 4);
    int*   counts = (int*)carve((size_t)n * 4);
    int*   head   = (int*)carve((size_t)n * 4);
    int*   nxt    = (int*)carve((size_t)nE * 4);
    unsigned short* Wp1 = (unsigned short*)carve(16384 * 2);
    unsigned short* Wp2 = (unsigned short*)carve(16384 * 2);
    unsigned short* Xb  = (unsigned short*)carve((size_t)npad * 128 * 2);
    unsigned short* Hs  = (unsigned short*)carve((size_t)npad * 128 * 2);
    unsigned short* Hb  = (unsigned short*)carve((size_t)npad * 128 * 2);

    dim3 blk(256);
    int nb_n = (n + 255) / 256;
    int nb_e = (nE + 255) / 256;
    int total = n * 128, total_pad = npad * 128;

    // graph structures + dinv
    init_k<<<nb_n, blk, 0, stream>>>(head, counts, n);
    build_k<<<nb_e, blk, 0, stream>>>(src, dst, head, nxt, counts, nE);
    dinv_k<<<nb_n, blk, 0, stream>>>(counts, dinv, n);

    // conversions
    convx_k<<<(total_pad + 255) / 256, blk, 0, stream>>>(x, Xb, total, total_pad);
    packw_k<<<32768 / 256, blk, 0, stream>>>(W1, W2, Wp1, Wp2);

    int nwave_blocks = (n + 3) / 4;

    // layer 1
    mfma_gemm_k<<<nblk64, blk, 0, stream>>>(Xb, Wp1, dinv, Hs, n);
    agg_ln_k<true><<<nwave_blocks, blk, 0, stream>>>(Hs, dinv, head, nxt, src, b1, g1, be1, Hb, n);

    // layer 2
    mfma_gemm_k<<<nblk64, blk, 0, stream>>>(Hb, Wp2, dinv, Hs, n);
    agg_ln_k<false><<<nwave_blocks, blk, 0, stream>>>(Hs, dinv, head, nxt, src, b2, g2, be2, out, n);
}

// Round 6
// 309.301 us; speedup vs baseline: 1.5276x; 1.2482x over previous
//
#include <hip/hip_runtime.h>

#define LN_EPS 1e-5f

typedef __attribute__((ext_vector_type(8))) short bf16x8;
typedef __attribute__((ext_vector_type(4))) float f32x4;

__device__ __forceinline__ unsigned short f2bf(float f) {
    union { float f; unsigned u; } x; x.f = f;
    unsigned r = (x.u + 0x7FFFu + ((x.u >> 16) & 1u)) >> 16;
    return (unsigned short)r;
}
__device__ __forceinline__ float bfbits2f(unsigned hi) {  // hi = bf16 bits already in [31:16]
    union { unsigned u; float f; } x; x.u = hi; return x.f;
}

// ---------- linked-list build ----------
__global__ void init_k(int* head, int* counts, int n) {
    int i = blockIdx.x * blockDim.x + threadIdx.x;
    if (i < n) { head[i] = -1; counts[i] = 0; }
}

// nxt2[e] = (src[e], previous head) written at index e (coalesced 8B).
// head/counts are 200KB, L2-resident, fan-in ~deg(16) -> low contention.
__global__ void build_k(const int* __restrict__ src, const int* __restrict__ dst,
                        int* head, int2* __restrict__ nxt2, int* counts, int nE) {
    int e = blockIdx.x * blockDim.x + threadIdx.x;
    if (e < nE) {
        int d = dst[e];
        int prev = atomicExch(&head[d], e);
        nxt2[e] = make_int2(src[e], prev);
        atomicAdd(&counts[d], 1);
    }
}

// ---------- scan: counts -> rowptr (+ dinv) ----------
__global__ __launch_bounds__(256) void scan1_k(const int* __restrict__ counts,
                                               int* __restrict__ incl,
                                               int* __restrict__ bsums, int n) {
    __shared__ int s[256];
    int i = blockIdx.x * 256 + threadIdx.x;
    int v = (i < n) ? counts[i] : 0;
    s[threadIdx.x] = v;
    __syncthreads();
    for (int off = 1; off < 256; off <<= 1) {
        int t = (threadIdx.x >= off) ? s[threadIdx.x - off] : 0;
        __syncthreads();
        s[threadIdx.x] += t;
        __syncthreads();
    }
    if (i < n) incl[i] = s[threadIdx.x];
    if (threadIdx.x == 255) bsums[blockIdx.x] = s[255];
}

__global__ __launch_bounds__(256) void scan2_k(int* bsums, int nb) {
    __shared__ int s[256];
    int v = (threadIdx.x < nb) ? bsums[threadIdx.x] : 0;
    s[threadIdx.x] = v;
    __syncthreads();
    for (int off = 1; off < 256; off <<= 1) {
        int t = (threadIdx.x >= off) ? s[threadIdx.x - off] : 0;
        __syncthreads();
        s[threadIdx.x] += t;
        __syncthreads();
    }
    if (threadIdx.x < nb) bsums[threadIdx.x] = s[threadIdx.x] - v;
}

__global__ __launch_bounds__(256) void scan3_k(const int* __restrict__ counts,
                                               const int* __restrict__ incl,
                                               const int* __restrict__ bsums,
                                               int* __restrict__ rowptr,
                                               float* __restrict__ dinv, int n, int nE) {
    int i = blockIdx.x * 256 + threadIdx.x;
    if (i < n) {
        rowptr[i] = incl[i] - counts[i] + bsums[blockIdx.x];
        dinv[i] = rsqrtf((float)(counts[i] + 1));
    }
    if (i == n) rowptr[n] = nE;
}

// ---------- list -> CSR: one thread per node, dense eidx writes ----------
__global__ void list2csr_k(const int* __restrict__ head, const int2* __restrict__ nxt2,
                           const int* __restrict__ rowptr, int* __restrict__ eidx, int n) {
    int i = blockIdx.x * blockDim.x + threadIdx.x;
    if (i >= n) return;
    int e = head[i];
    int pos = rowptr[i];
    while (e >= 0) {
        int2 p = nxt2[e];
        eidx[pos++] = p.x;
        e = p.y;
    }
}

// ---------- conversions / packing ----------
__global__ void convx_k(const float* __restrict__ X, unsigned short* __restrict__ Xb,
                        int total, int total_pad) {
    int i = blockIdx.x * blockDim.x + threadIdx.x;
    if (i < total_pad) Xb[i] = (i < total) ? f2bf(X[i]) : (unsigned short)0;
}

// Pack both W1 and W2 into B-fragment-contiguous bf16 layout:
// Wp[(((kc*128 + col)*4 + kb)*8) + j] = W[(kc*32 + kb*8 + j)*128 + col]
__global__ void packw_k(const float* __restrict__ W1, const float* __restrict__ W2,
                        unsigned short* __restrict__ Wp1, unsigned short* __restrict__ Wp2) {
    int idx = blockIdx.x * blockDim.x + threadIdx.x;  // 0..32767
    const float* W = (idx < 16384) ? W1 : W2;
    unsigned short* Wp = (idx < 16384) ? Wp1 : Wp2;
    int t = idx & 16383;
    int k = t >> 7, col = t & 127;
    int kc = k >> 5, kr = k & 31, kb = kr >> 3, j = kr & 7;
    Wp[(((kc * 128 + col) * 4 + kb) * 8) + j] = f2bf(W[k * 128 + col]);
}

// ---------- MFMA GEMM: Y[r,:] = bf16( dinv[r] * (Xb[r,:] @ W) ) ----------
__global__ __launch_bounds__(256) void mfma_gemm_k(const unsigned short* __restrict__ Xb,
                                                   const unsigned short* __restrict__ Wp,
                                                   const float* __restrict__ dinv,
                                                   unsigned short* __restrict__ Y, int n) {
    int wid = threadIdx.x >> 6;
    int lane = threadIdx.x & 63;
    int rgrp = wid & 1;
    int cgrp = wid >> 1;
    int row0 = blockIdx.x * 64 + rgrp * 32;
    int m = lane & 15;
    int kb = lane >> 4;  // 0..3

    f32x4 acc[2][4] = {};
#pragma unroll
    for (int kc = 0; kc < 4; ++kc) {
        bf16x8 a[2], b[4];
#pragma unroll
        for (int rs = 0; rs < 2; ++rs) {
            int r = row0 + rs * 16 + m;
            a[rs] = *(const bf16x8*)(Xb + (size_t)r * 128 + kc * 32 + kb * 8);
        }
#pragma unroll
        for (int cf = 0; cf < 4; ++cf) {
            int col = cgrp * 64 + cf * 16 + m;
            b[cf] = *(const bf16x8*)(Wp + (((kc * 128 + col) * 4 + kb) * 8));
        }
#pragma unroll
        for (int rs = 0; rs < 2; ++rs)
#pragma unroll
            for (int cf = 0; cf < 4; ++cf)
                acc[rs][cf] = __builtin_amdgcn_mfma_f32_16x16x32_bf16(a[rs], b[cf], acc[rs][cf], 0, 0, 0);
    }
    // D layout: row = (lane>>4)*4 + reg, col = lane&15
#pragma unroll
    for (int rs = 0; rs < 2; ++rs) {
        int rbase = row0 + rs * 16 + kb * 4;
#pragma unroll
        for (int r = 0; r < 4; ++r) {
            int row = rbase + r;
            if (row >= n) continue;
            float dv = dinv[row];
#pragma unroll
            for (int cf = 0; cf < 4; ++cf) {
                int col = cgrp * 64 + cf * 16 + m;
                Y[(size_t)row * 128 + col] = f2bf(acc[rs][cf][r] * dv);
            }
        }
    }
}

// ---------- fused CSR gather-aggregate + bias + LN + ReLU ----------
template <bool OUT_BF16>
__global__ __launch_bounds__(256) void agg_ln_k(const unsigned short* __restrict__ Hs,
                                                const float* __restrict__ dinv,
                                                const int* __restrict__ rowptr,
                                                const int* __restrict__ eidx,
                                                const float* __restrict__ bias,
                                                const float* __restrict__ g,
                                                const float* __restrict__ beta,
                                                void* __restrict__ out, int n) {
    int wave = (blockIdx.x * blockDim.x + threadIdx.x) >> 6;
    int lane = threadIdx.x & 63;
    if (wave >= n) return;
    const unsigned* H4 = (const unsigned*)Hs;  // one uint = 2 bf16
    unsigned v0 = H4[(size_t)wave * 64 + lane];
    float ax = bfbits2f(v0 << 16);
    float ay = bfbits2f(v0 & 0xFFFF0000u);
    int beg = rowptr[wave];
    int end = rowptr[wave + 1];
    int e = beg;
    for (; e + 3 < end; e += 4) {
        int s0 = eidx[e], s1 = eidx[e + 1], s2 = eidx[e + 2], s3 = eidx[e + 3];
        unsigned u0 = H4[(size_t)s0 * 64 + lane];
        unsigned u1 = H4[(size_t)s1 * 64 + lane];
        unsigned u2 = H4[(size_t)s2 * 64 + lane];
        unsigned u3 = H4[(size_t)s3 * 64 + lane];
        ax += bfbits2f(u0 << 16) + bfbits2f(u1 << 16) + bfbits2f(u2 << 16) + bfbits2f(u3 << 16);
        ay += bfbits2f(u0 & 0xFFFF0000u) + bfbits2f(u1 & 0xFFFF0000u) +
              bfbits2f(u2 & 0xFFFF0000u) + bfbits2f(u3 & 0xFFFF0000u);
    }
    for (; e < end; ++e) {
        unsigned u0 = H4[(size_t)eidx[e] * 64 + lane];
        ax += bfbits2f(u0 << 16);
        ay += bfbits2f(u0 & 0xFFFF0000u);
    }
    float dt = dinv[wave];
    float vx = ax * dt + bias[2 * lane];
    float vy = ay * dt + bias[2 * lane + 1];
    float sum = vx + vy;
#pragma unroll
    for (int off = 32; off > 0; off >>= 1) sum += __shfl_down(sum, off);
    sum = __shfl(sum, 0);
    float mu = sum * (1.0f / 128.0f);
    float dx = vx - mu, dy = vy - mu;
    float vs = dx * dx + dy * dy;
#pragma unroll
    for (int off = 32; off > 0; off >>= 1) vs += __shfl_down(vs, off);
    vs = __shfl(vs, 0);
    float rstd = rsqrtf(vs * (1.0f / 128.0f) + LN_EPS);
    float o0 = fmaxf(dx * rstd * g[2 * lane] + beta[2 * lane], 0.0f);
    float o1 = fmaxf(dy * rstd * g[2 * lane + 1] + beta[2 * lane + 1], 0.0f);
    if (OUT_BF16) {
        unsigned pack = (unsigned)f2bf(o0) | ((unsigned)f2bf(o1) << 16);
        ((unsigned*)out)[(size_t)wave * 64 + lane] = pack;
    } else {
        ((float2*)out)[(size_t)wave * 64 + lane] = make_float2(o0, o1);
    }
}

extern "C" void kernel_launch(void* const* d_in, const int* in_sizes, int n_in,
                              void* d_out, int out_size, void* d_ws, size_t ws_size,
                              hipStream_t stream) {
    const float* x   = (const float*)d_in[0];
    const int*   ei  = (const int*)d_in[1];
    const float* W1  = (const float*)d_in[2];
    const float* b1  = (const float*)d_in[3];
    const float* g1  = (const float*)d_in[4];
    const float* be1 = (const float*)d_in[5];
    const float* W2  = (const float*)d_in[6];
    const float* b2  = (const float*)d_in[7];
    const float* g2  = (const float*)d_in[8];
    const float* be2 = (const float*)d_in[9];
    float* out = (float*)d_out;

    int n  = in_sizes[0] / 128;   // 50000
    int nE = in_sizes[1] / 2;     // 800000
    const int* src = ei;
    const int* dst = ei + nE;

    int nblk64 = (n + 63) / 64;   // GEMM blocks
    int npad   = nblk64 * 64;     // padded rows for OOB-safe frag loads

    char* p = (char*)d_ws;
    auto carve = [&](size_t bytes) {
        char* r = p;
        p += (bytes + 255) & ~(size_t)255;
        return r;
    };
    float* dinv   = (float*)carve((size_t)n * 4);
    int*   counts = (int*)carve((size_t)n * 4);
    int*   head   = (int*)carve((size_t)n * 4);
    int*   incl   = (int*)carve((size_t)n * 4);
    int*   bsums  = (int*)carve(256 * 4);
    int*   rowptr = (int*)carve((size_t)(n + 1) * 4);
    int2*  nxt2   = (int2*)carve((size_t)nE * 8);
    int*   eidx   = (int*)carve((size_t)nE * 4);
    unsigned short* Wp1 = (unsigned short*)carve(16384 * 2);
    unsigned short* Wp2 = (unsigned short*)carve(16384 * 2);
    unsigned short* Xb  = (unsigned short*)carve((size_t)npad * 128 * 2);
    unsigned short* Hs  = (unsigned short*)carve((size_t)npad * 128 * 2);
    unsigned short* Hb  = (unsigned short*)carve((size_t)npad * 128 * 2);

    dim3 blk(256);
    int nb_n = (n + 255) / 256;
    int nb_e = (nE + 255) / 256;
    int total = n * 128, total_pad = npad * 128;

    // graph structures: list build -> scan -> CSR
    init_k<<<nb_n, blk, 0, stream>>>(head, counts, n);
    build_k<<<nb_e, blk, 0, stream>>>(src, dst, head, nxt2, counts, nE);
    scan1_k<<<nb_n, blk, 0, stream>>>(counts, incl, bsums, n);
    scan2_k<<<1, blk, 0, stream>>>(bsums, nb_n);
    scan3_k<<<(n + 256) / 256, blk, 0, stream>>>(counts, incl, bsums, rowptr, dinv, n, nE);
    list2csr_k<<<nb_n, blk, 0, stream>>>(head, nxt2, rowptr, eidx, n);

    // conversions
    convx_k<<<(total_pad + 255) / 256, blk, 0, stream>>>(x, Xb, total, total_pad);
    packw_k<<<32768 / 256, blk, 0, stream>>>(W1, W2, Wp1, Wp2);

    int nwave_blocks = (n + 3) / 4;

    // layer 1
    mfma_gemm_k<<<nblk64, blk, 0, stream>>>(Xb, Wp1, dinv, Hs, n);
    agg_ln_k<true><<<nwave_blocks, blk, 0, stream>>>(Hs, dinv, rowptr, eidx, b1, g1, be1, Hb, n);

    // layer 2
    mfma_gemm_k<<<nblk64, blk, 0, stream>>>(Hb, Wp2, dinv, Hs, n);
    agg_ln_k<false><<<nwave_blocks, blk, 0, stream>>>(Hs, dinv, rowptr, eidx, b2, g2, be2, out, n);
}